// Round 1
// baseline (3299.211 us; speedup 1.0000x reference)
//
#include <hip/hip_runtime.h>
#include <hip/hip_bf16.h>

#define N_NODES 50000
#define E_EDGES 1600000
#define EP (E_EDGES + N_NODES)   // edges + self loops = 1650000
#define IN_CH 128
#define HID 32
#define HEADS 4
#define HC (HEADS * HID)         // 128
#define OUT_CH 16
#define B_GRAPHS 512
#define NEG_SLOPE 0.2f

// ---------------- K1: h = x @ W1  (N x 128) @ (128 x 128) ----------------
#define NPB 32
__global__ __launch_bounds__(256) void k_gemm_h(const float* __restrict__ x,
                                                const float* __restrict__ W1,
                                                float* __restrict__ h) {
    __shared__ float sX[NPB][IN_CH];   // 16 KB
    __shared__ float sW[32][HC];       // 16 KB
    const int t = threadIdx.x;
    const int n0 = blockIdx.x * NPB;

    for (int i = t; i < NPB * IN_CH; i += 256) {
        int n = n0 + (i >> 7);
        sX[i >> 7][i & 127] = (n < N_NODES) ? x[(size_t)n * IN_CH + (i & 127)] : 0.f;
    }

    float acc[16];
#pragma unroll
    for (int i = 0; i < 16; i++) acc[i] = 0.f;
    const int tx = t & 127;   // output column
    const int ty = t >> 7;    // 0/1

    for (int kb = 0; kb < 4; kb++) {
        __syncthreads();
        for (int i = t; i < 32 * HC; i += 256) {
            sW[i >> 7][i & 127] = W1[(size_t)(kb * 32 + (i >> 7)) * HC + (i & 127)];
        }
        __syncthreads();
#pragma unroll
        for (int kk = 0; kk < 32; kk++) {
            float w = sW[kk][tx];
#pragma unroll
            for (int i = 0; i < 16; i++) {
                acc[i] += sX[2 * i + ty][kb * 32 + kk] * w;
            }
        }
    }
#pragma unroll
    for (int i = 0; i < 16; i++) {
        int n = n0 + 2 * i + ty;
        if (n < N_NODES) h[(size_t)n * HC + tx] = acc[i];
    }
}

// ---------------- K1b: a_s[n,h] = <h[n,h,:], att_src[h,:]>, same for dst --
__global__ __launch_bounds__(256) void k_attn_scores(const float* __restrict__ h,
                                                     const float* __restrict__ att_src,
                                                     const float* __restrict__ att_dst,
                                                     float* __restrict__ a_s,
                                                     float* __restrict__ a_d) {
    int idx = blockIdx.x * 256 + threadIdx.x;   // one per (node, head)
    if (idx >= N_NODES * HEADS) return;
    int n = idx >> 2, hd = idx & 3;
    const float4* hp  = (const float4*)(h + (size_t)n * HC + hd * HID);
    const float4* asp = (const float4*)(att_src + hd * HID);
    const float4* adp = (const float4*)(att_dst + hd * HID);
    float s = 0.f, d = 0.f;
#pragma unroll
    for (int i = 0; i < 8; i++) {
        float4 hv = hp[i], av = asp[i], dv = adp[i];
        s += hv.x * av.x + hv.y * av.y + hv.z * av.z + hv.w * av.w;
        d += hv.x * dv.x + hv.y * dv.y + hv.z * dv.z + hv.w * dv.w;
    }
    a_s[idx] = s;
    a_d[idx] = d;
}

// ---------------- K2: per-edge softmax numerator + denominator -----------
__device__ __forceinline__ float lrelu_exp(float v) {
    v = v > 0.f ? v : NEG_SLOPE * v;
    return __expf(v);
}

__global__ __launch_bounds__(256) void k_edge_num(const int* __restrict__ ei,
                                                  const float* __restrict__ a_s,
                                                  const float* __restrict__ a_d,
                                                  float* __restrict__ exv,
                                                  float* __restrict__ den) {
    int e = blockIdx.x * 256 + threadIdx.x;
    if (e >= EP) return;
    int s, d;
    if (e < E_EDGES) { s = ei[e]; d = ei[E_EDGES + e]; }
    else             { s = d = e - E_EDGES; }
    float4 as = *(const float4*)(a_s + (size_t)s * 4);
    float4 ad = *(const float4*)(a_d + (size_t)d * 4);
    float4 ev;
    ev.x = lrelu_exp(as.x + ad.x);
    ev.y = lrelu_exp(as.y + ad.y);
    ev.z = lrelu_exp(as.z + ad.z);
    ev.w = lrelu_exp(as.w + ad.w);
    *(float4*)(exv + (size_t)e * 4) = ev;
    float* dp = den + (size_t)d * 4;
    atomicAdd(dp + 0, ev.x);
    atomicAdd(dp + 1, ev.y);
    atomicAdd(dp + 2, ev.z);
    atomicAdd(dp + 3, ev.w);
}

// ---------------- K3: out[dst] += h[src] * a  (atomic scatter) -----------
// 32 threads per edge, float4 per thread (8 edges / block of 256)
__global__ __launch_bounds__(256) void k_aggregate(const int* __restrict__ ei,
                                                   const float* __restrict__ hfeat,
                                                   const float* __restrict__ exv,
                                                   const float* __restrict__ den,
                                                   float* __restrict__ outacc) {
    const int t = threadIdx.x;
    long long eidx = (long long)blockIdx.x * 8 + (t >> 5);
    if (eidx >= EP) return;
    int e = (int)eidx;
    int lane = t & 31;
    int c4 = lane * 4;
    int head = c4 >> 5;
    int s, d;
    if (e < E_EDGES) { s = ei[e]; d = ei[E_EDGES + e]; }
    else             { s = d = e - E_EDGES; }
    float w = exv[(size_t)e * 4 + head] / (den[(size_t)d * 4 + head] + 1e-16f);
    float4 hv = *(const float4*)(hfeat + (size_t)s * HC + c4);
    float* op = outacc + (size_t)d * HC + c4;
    atomicAdd(op + 0, hv.x * w);
    atomicAdd(op + 1, hv.y * w);
    atomicAdd(op + 2, hv.z * w);
    atomicAdd(op + 3, hv.w * w);
}

// ---------------- K4: elu(out + b1), pool by sorted batch ----------------
#define POOL_NODES 64
__global__ __launch_bounds__(128) void k_elu_pool(const float* __restrict__ outacc,
                                                  const float* __restrict__ b1,
                                                  const int* __restrict__ batch,
                                                  float* __restrict__ g) {
    const int f = threadIdx.x;   // 0..127
    int n0 = blockIdx.x * POOL_NODES;
    int nend = n0 + POOL_NODES;
    if (nend > N_NODES) nend = N_NODES;
    if (n0 >= N_NODES) return;
    float bias = b1[f];
    float accum = 0.f;
    int cur = batch[n0];
    for (int n = n0; n < nend; n++) {
        int b = batch[n];
        if (b != cur) {
            atomicAdd(&g[(size_t)cur * HC + f], accum);
            accum = 0.f;
            cur = b;
        }
        float v = outacc[(size_t)n * HC + f] + bias;
        v = v > 0.f ? v : (__expf(v) - 1.f);
        accum += v;
    }
    atomicAdd(&g[(size_t)cur * HC + f], accum);
}

// ---------------- K5: g @ lin1 + b -> relu? no -> @ lin2 + b -------------
__global__ __launch_bounds__(64) void k_mlp(const float* __restrict__ g,
                                            const float* __restrict__ w1,
                                            const float* __restrict__ bb1,
                                            const float* __restrict__ w2,
                                            const float* __restrict__ bb2,
                                            float* __restrict__ out) {
    __shared__ float sg[HC];
    __shared__ float st[HID];
    int b = blockIdx.x;
    int t = threadIdx.x;   // 64
    sg[t]      = g[(size_t)b * HC + t];
    sg[t + 64] = g[(size_t)b * HC + 64 + t];
    __syncthreads();
    if (t < HID) {
        float acc = bb1[t];
#pragma unroll 8
        for (int k = 0; k < HC; k++) acc += sg[k] * w1[(size_t)k * HID + t];
        st[t] = acc;
    }
    __syncthreads();
    if (t < OUT_CH) {
        float acc = bb2[t];
#pragma unroll
        for (int k = 0; k < HID; k++) acc += st[k] * w2[(size_t)k * OUT_CH + t];
        out[(size_t)b * OUT_CH + t] = acc;
    }
}

extern "C" void kernel_launch(void* const* d_in, const int* in_sizes, int n_in,
                              void* d_out, int out_size, void* d_ws, size_t ws_size,
                              hipStream_t stream) {
    const float* x       = (const float*)d_in[0];
    const int*   ei      = (const int*)d_in[1];
    const int*   batch   = (const int*)d_in[2];
    const float* W1      = (const float*)d_in[3];
    const float* att_src = (const float*)d_in[4];
    const float* att_dst = (const float*)d_in[5];
    const float* b1      = (const float*)d_in[6];
    const float* lin1_w  = (const float*)d_in[7];
    const float* lin1_b  = (const float*)d_in[8];
    const float* lin2_w  = (const float*)d_in[9];
    const float* lin2_b  = (const float*)d_in[10];
    float* out = (float*)d_out;

    float* ws = (float*)d_ws;
    float* h      = ws;                          // N*128
    float* a_s    = h + (size_t)N_NODES * HC;    // N*4
    float* a_d    = a_s + (size_t)N_NODES * 4;   // N*4
    float* exv    = a_d + (size_t)N_NODES * 4;   // EP*4
    float* den    = exv + (size_t)EP * 4;        // N*4
    float* outacc = den + (size_t)N_NODES * 4;   // N*128
    float* g      = outacc + (size_t)N_NODES * HC; // B*128

    hipMemsetAsync(den, 0, (size_t)N_NODES * 4 * sizeof(float), stream);
    hipMemsetAsync(outacc, 0, (size_t)N_NODES * HC * sizeof(float), stream);
    hipMemsetAsync(g, 0, (size_t)B_GRAPHS * HC * sizeof(float), stream);

    k_gemm_h<<<(N_NODES + NPB - 1) / NPB, 256, 0, stream>>>(x, W1, h);
    k_attn_scores<<<(N_NODES * HEADS + 255) / 256, 256, 0, stream>>>(h, att_src, att_dst, a_s, a_d);
    k_edge_num<<<(EP + 255) / 256, 256, 0, stream>>>(ei, a_s, a_d, exv, den);
    k_aggregate<<<(EP + 7) / 8, 256, 0, stream>>>(ei, h, exv, den, outacc);
    k_elu_pool<<<(N_NODES + POOL_NODES - 1) / POOL_NODES, 128, 0, stream>>>(outacc, b1, batch, g);
    k_mlp<<<B_GRAPHS, 64, 0, stream>>>(g, lin1_w, lin1_b, lin2_w, lin2_b, out);
}

// Round 2
// 589.778 us; speedup vs baseline: 5.5940x; 5.5940x over previous
//
#include <hip/hip_runtime.h>
#include <hip/hip_bf16.h>

#define N_NODES 50000
#define E_EDGES 1600000
#define EP (E_EDGES + N_NODES)   // edges + self loops = 1650000
#define IN_CH 128
#define HID 32
#define HEADS 4
#define HC (HEADS * HID)         // 128
#define OUT_CH 16
#define B_GRAPHS 512
#define NEG_SLOPE 0.2f

// ---------------- K1: h = x @ W1  (N x 128) @ (128 x 128) ----------------
#define NPB 32
__global__ __launch_bounds__(256) void k_gemm_h(const float* __restrict__ x,
                                                const float* __restrict__ W1,
                                                float* __restrict__ h) {
    __shared__ float sX[NPB][IN_CH];   // 16 KB
    __shared__ float sW[32][HC];       // 16 KB
    const int t = threadIdx.x;
    const int n0 = blockIdx.x * NPB;

    for (int i = t; i < NPB * IN_CH; i += 256) {
        int n = n0 + (i >> 7);
        sX[i >> 7][i & 127] = (n < N_NODES) ? x[(size_t)n * IN_CH + (i & 127)] : 0.f;
    }

    float acc[16];
#pragma unroll
    for (int i = 0; i < 16; i++) acc[i] = 0.f;
    const int tx = t & 127;   // output column
    const int ty = t >> 7;    // 0/1

    for (int kb = 0; kb < 4; kb++) {
        __syncthreads();
        for (int i = t; i < 32 * HC; i += 256) {
            sW[i >> 7][i & 127] = W1[(size_t)(kb * 32 + (i >> 7)) * HC + (i & 127)];
        }
        __syncthreads();
#pragma unroll
        for (int kk = 0; kk < 32; kk++) {
            float w = sW[kk][tx];
#pragma unroll
            for (int i = 0; i < 16; i++) {
                acc[i] += sX[2 * i + ty][kb * 32 + kk] * w;
            }
        }
    }
#pragma unroll
    for (int i = 0; i < 16; i++) {
        int n = n0 + 2 * i + ty;
        if (n < N_NODES) h[(size_t)n * HC + tx] = acc[i];
    }
}

// ---------------- K1b: a_s[n,h] = <h[n,h,:], att_src[h,:]>, same for dst --
__global__ __launch_bounds__(256) void k_attn_scores(const float* __restrict__ h,
                                                     const float* __restrict__ att_src,
                                                     const float* __restrict__ att_dst,
                                                     float* __restrict__ a_s,
                                                     float* __restrict__ a_d) {
    int idx = blockIdx.x * 256 + threadIdx.x;   // one per (node, head)
    if (idx >= N_NODES * HEADS) return;
    int n = idx >> 2, hd = idx & 3;
    const float4* hp  = (const float4*)(h + (size_t)n * HC + hd * HID);
    const float4* asp = (const float4*)(att_src + hd * HID);
    const float4* adp = (const float4*)(att_dst + hd * HID);
    float s = 0.f, d = 0.f;
#pragma unroll
    for (int i = 0; i < 8; i++) {
        float4 hv = hp[i], av = asp[i], dv = adp[i];
        s += hv.x * av.x + hv.y * av.y + hv.z * av.z + hv.w * av.w;
        d += hv.x * dv.x + hv.y * dv.y + hv.z * dv.z + hv.w * dv.w;
    }
    a_s[idx] = s;
    a_d[idx] = d;
}

// ---------------- K2: in-degree count per destination --------------------
__global__ __launch_bounds__(256) void k_count(const int* __restrict__ ei,
                                               int* __restrict__ deg) {
    int e = blockIdx.x * 256 + threadIdx.x;
    if (e >= EP) return;
    int d = (e < E_EDGES) ? ei[E_EDGES + e] : (e - E_EDGES);
    atomicAdd(&deg[d], 1);
}

// ---------------- K3: exclusive scan of deg -> off, cursor ---------------
__global__ __launch_bounds__(1024) void k_scan(const int* __restrict__ deg,
                                               int* __restrict__ off,
                                               int* __restrict__ cursor) {
    __shared__ int s[1024];
    __shared__ int carry;
    const int t = threadIdx.x;
    if (t == 0) carry = 0;
    __syncthreads();
    for (int base = 0; base < N_NODES; base += 1024) {
        int i = base + t;
        int v = (i < N_NODES) ? deg[i] : 0;
        s[t] = v;
        __syncthreads();
        for (int dlt = 1; dlt < 1024; dlt <<= 1) {
            int add = (t >= dlt) ? s[t - dlt] : 0;
            __syncthreads();
            s[t] += add;
            __syncthreads();
        }
        int excl = carry + s[t] - v;
        if (i < N_NODES) { off[i] = excl; cursor[i] = excl; }
        int total = s[1023];
        __syncthreads();
        if (t == 0) carry += total;
        __syncthreads();
    }
    if (t == 0) off[N_NODES] = EP;
}

// ---------------- K4: scatter edges into CSR (src id + exp weight) -------
__device__ __forceinline__ float lrelu_exp(float v) {
    v = v > 0.f ? v : NEG_SLOPE * v;
    return __expf(v);
}

__global__ __launch_bounds__(256) void k_scatter(const int* __restrict__ ei,
                                                 const float* __restrict__ a_s,
                                                 const float* __restrict__ a_d,
                                                 int* __restrict__ cursor,
                                                 int* __restrict__ csr_src,
                                                 float4* __restrict__ csr_ev) {
    int e = blockIdx.x * 256 + threadIdx.x;
    if (e >= EP) return;
    int s, d;
    if (e < E_EDGES) { s = ei[e]; d = ei[E_EDGES + e]; }
    else             { s = d = e - E_EDGES; }
    float4 as = *(const float4*)(a_s + (size_t)s * 4);
    float4 ad = *(const float4*)(a_d + (size_t)d * 4);
    float4 ev;
    ev.x = lrelu_exp(as.x + ad.x);
    ev.y = lrelu_exp(as.y + ad.y);
    ev.z = lrelu_exp(as.z + ad.z);
    ev.w = lrelu_exp(as.w + ad.w);
    int pos = atomicAdd(&cursor[d], 1);
    csr_src[pos] = s;
    csr_ev[pos] = ev;
}

// ---------------- K5: CSR gather-aggregate + ELU + batch pool ------------
// 128 threads per block, one feature channel per thread, AGG_CHUNK nodes/block.
#define AGG_CHUNK 8
__global__ __launch_bounds__(128) void k_agg_pool(const int* __restrict__ off,
                                                  const int* __restrict__ csr_src,
                                                  const float4* __restrict__ csr_ev,
                                                  const float* __restrict__ h,
                                                  const float* __restrict__ b1,
                                                  const int* __restrict__ batch,
                                                  float* __restrict__ g) {
    const int f = threadIdx.x;       // 0..127 feature channel
    const int head = f >> 5;         // 0..3
    const int n0 = blockIdx.x * AGG_CHUNK;
    int n1 = n0 + AGG_CHUNK;
    if (n1 > N_NODES) n1 = N_NODES;
    const float bias = b1[f];
    float pool = 0.f;
    int cur = batch[n0];
    for (int n = n0; n < n1; n++) {
        int b = batch[n];
        if (b != cur) {                        // uniform branch (same n for all)
            atomicAdd(&g[(size_t)cur * HC + f], pool);
            pool = 0.f;
            cur = b;
        }
        const int rs = off[n], re = off[n + 1];
        float acc = 0.f, dsum = 0.f;
#pragma unroll 2
        for (int i = rs; i < re; i++) {
            int s = csr_src[i];                              // scalar broadcast
            float w = ((const float*)(csr_ev + i))[head];    // 4-way broadcast
            dsum += w;
            acc += w * h[(size_t)s * HC + f];                // coalesced 512B
        }
        float inv = 1.f / (dsum + 1e-16f);
        float v = acc * inv + bias;
        v = v > 0.f ? v : (__expf(v) - 1.f);                 // ELU
        pool += v;
    }
    atomicAdd(&g[(size_t)cur * HC + f], pool);
}

// ---------------- K6: tiny 2-layer MLP on pooled graphs ------------------
__global__ __launch_bounds__(64) void k_mlp(const float* __restrict__ g,
                                            const float* __restrict__ w1,
                                            const float* __restrict__ bb1,
                                            const float* __restrict__ w2,
                                            const float* __restrict__ bb2,
                                            float* __restrict__ out) {
    __shared__ float sg[HC];
    __shared__ float st[HID];
    int b = blockIdx.x;
    int t = threadIdx.x;   // 64
    sg[t]      = g[(size_t)b * HC + t];
    sg[t + 64] = g[(size_t)b * HC + 64 + t];
    __syncthreads();
    if (t < HID) {
        float acc = bb1[t];
#pragma unroll 8
        for (int k = 0; k < HC; k++) acc += sg[k] * w1[(size_t)k * HID + t];
        st[t] = acc;
    }
    __syncthreads();
    if (t < OUT_CH) {
        float acc = bb2[t];
#pragma unroll
        for (int k = 0; k < HID; k++) acc += st[k] * w2[(size_t)k * OUT_CH + t];
        out[(size_t)b * OUT_CH + t] = acc;
    }
}

extern "C" void kernel_launch(void* const* d_in, const int* in_sizes, int n_in,
                              void* d_out, int out_size, void* d_ws, size_t ws_size,
                              hipStream_t stream) {
    const float* x       = (const float*)d_in[0];
    const int*   ei      = (const int*)d_in[1];
    const int*   batch   = (const int*)d_in[2];
    const float* W1      = (const float*)d_in[3];
    const float* att_src = (const float*)d_in[4];
    const float* att_dst = (const float*)d_in[5];
    const float* b1      = (const float*)d_in[6];
    const float* lin1_w  = (const float*)d_in[7];
    const float* lin1_b  = (const float*)d_in[8];
    const float* lin2_w  = (const float*)d_in[9];
    const float* lin2_b  = (const float*)d_in[10];
    float* out = (float*)d_out;

    float* ws = (float*)d_ws;
    // layout (float offsets):
    float*  h       = ws;                         // 6,400,000  (N*128)
    float*  a_s     = ws + 6400000;               //   200,000  (N*4)
    float*  a_d     = ws + 6600000;               //   200,000  (N*4)
    float4* csr_ev  = (float4*)(ws + 6800000);    // 6,600,000 floats (EP*4), 16B aligned
    int*    csr_src = (int*)(ws + 13400000);      // 1,650,000
    int*    deg     = (int*)(ws + 15050000);      //    50,000
    int*    off     = (int*)(ws + 15100000);      //    50,001 (pad to 50,016)
    int*    cursor  = (int*)(ws + 15150016);      //    50,000
    float*  g       = ws + 15200016;              //    65,536 (B*128)

    hipMemsetAsync(deg, 0, (size_t)N_NODES * sizeof(int), stream);
    hipMemsetAsync(g, 0, (size_t)B_GRAPHS * HC * sizeof(float), stream);

    k_gemm_h<<<(N_NODES + NPB - 1) / NPB, 256, 0, stream>>>(x, W1, h);
    k_attn_scores<<<(N_NODES * HEADS + 255) / 256, 256, 0, stream>>>(h, att_src, att_dst, a_s, a_d);
    k_count<<<(EP + 255) / 256, 256, 0, stream>>>(ei, deg);
    k_scan<<<1, 1024, 0, stream>>>(deg, off, cursor);
    k_scatter<<<(EP + 255) / 256, 256, 0, stream>>>(ei, a_s, a_d, cursor, csr_src, csr_ev);
    k_agg_pool<<<(N_NODES + AGG_CHUNK - 1) / AGG_CHUNK, 128, 0, stream>>>(off, csr_src, csr_ev, h, b1, batch, g);
    k_mlp<<<B_GRAPHS, 64, 0, stream>>>(g, lin1_w, lin1_b, lin2_w, lin2_b, out);
}

// Round 3
// 511.954 us; speedup vs baseline: 6.4443x; 1.1520x over previous
//
#include <hip/hip_runtime.h>
#include <hip/hip_bf16.h>

#define N_NODES 50000
#define E_EDGES 1600000
#define EP (E_EDGES + N_NODES)   // edges + self loops = 1650000
#define IN_CH 128
#define HID 32
#define HEADS 4
#define HC (HEADS * HID)         // 128
#define OUT_CH 16
#define B_GRAPHS 512
#define NEG_SLOPE 0.2f
#define SCAN_BLOCKS 49           // ceil(50000 / 1024)

// ---------------- K1: h = x @ W1 (+ fused attention scores + deg zero) ---
#define NPB 32
__global__ __launch_bounds__(256) void k_gemm_h(const float* __restrict__ x,
                                                const float* __restrict__ W1,
                                                const float* __restrict__ att_src,
                                                const float* __restrict__ att_dst,
                                                float* __restrict__ h,
                                                float* __restrict__ a_s,
                                                float* __restrict__ a_d,
                                                int* __restrict__ deg) {
    __shared__ float smem[8192];          // sX[32*128] | sW[32*128]; sH aliases later
    float* sX = smem;
    float* sW = smem + 4096;
    const int t = threadIdx.x;
    const int n0 = blockIdx.x * NPB;

    // fused: zero deg for the count kernel
    int gtid = blockIdx.x * 256 + t;
    if (gtid < N_NODES) deg[gtid] = 0;

    for (int i = t; i < NPB * IN_CH; i += 256) {
        int n = n0 + (i >> 7);
        sX[i] = (n < N_NODES) ? x[(size_t)n * IN_CH + (i & 127)] : 0.f;
    }

    float acc[16];
#pragma unroll
    for (int i = 0; i < 16; i++) acc[i] = 0.f;
    const int tx = t & 127;   // output column
    const int ty = t >> 7;    // 0/1

    for (int kb = 0; kb < 4; kb++) {
        __syncthreads();
        for (int i = t; i < 32 * HC; i += 256) {
            sW[i] = W1[(size_t)(kb * 32 + (i >> 7)) * HC + (i & 127)];
        }
        __syncthreads();
#pragma unroll
        for (int kk = 0; kk < 32; kk++) {
            float w = sW[kk * HC + tx];
#pragma unroll
            for (int i = 0; i < 16; i++) {
                acc[i] += sX[(2 * i + ty) * IN_CH + kb * 32 + kk] * w;
            }
        }
    }
#pragma unroll
    for (int i = 0; i < 16; i++) {
        int n = n0 + 2 * i + ty;
        if (n < N_NODES) h[(size_t)n * HC + tx] = acc[i];
    }

    // ---- fused attention scores: restash tile to LDS (pad 129), dot with att ----
    __syncthreads();                       // done reading sX/sW
    float* sH = smem;                      // 32 rows x 129 floats = 4128 <= 8192
#pragma unroll
    for (int i = 0; i < 16; i++) sH[(2 * i + ty) * 129 + tx] = acc[i];
    __syncthreads();
    if (t < 64) {
        int r = t & 31;
        int n = n0 + r;
        const float* __restrict__ av = (t < 32) ? att_src : att_dst;
        float s0 = 0.f, s1 = 0.f, s2 = 0.f, s3 = 0.f;
#pragma unroll 4
        for (int j = 0; j < 32; j++) {
            float* row = sH + r * 129 + j;
            s0 += row[0]  * av[j];
            s1 += row[32] * av[32 + j];
            s2 += row[64] * av[64 + j];
            s3 += row[96] * av[96 + j];
        }
        if (n < N_NODES) {
            float* dst = (t < 32) ? a_s : a_d;
            *(float4*)(dst + (size_t)n * 4) = make_float4(s0, s1, s2, s3);
        }
    }
}

// ---------------- K2: in-degree count per destination (+ g zero) ---------
__global__ __launch_bounds__(256) void k_count(const int* __restrict__ ei,
                                               int* __restrict__ deg,
                                               float* __restrict__ g) {
    int e = blockIdx.x * 256 + threadIdx.x;
    if (e < B_GRAPHS * HC) g[e] = 0.f;
    if (e >= EP) return;
    int d = (e < E_EDGES) ? ei[E_EDGES + e] : (e - E_EDGES);
    atomicAdd(&deg[d], 1);
}

// ---------------- K3a: per-block exclusive scan (1024 elems/block) -------
__global__ __launch_bounds__(256) void k_scan1(const int* __restrict__ deg,
                                               int* __restrict__ off,
                                               int* __restrict__ partial) {
    __shared__ int s[256];
    const int t = threadIdx.x;
    const int base = blockIdx.x * 1024 + t * 4;
    int v0 = (base + 0 < N_NODES) ? deg[base + 0] : 0;
    int v1 = (base + 1 < N_NODES) ? deg[base + 1] : 0;
    int v2 = (base + 2 < N_NODES) ? deg[base + 2] : 0;
    int v3 = (base + 3 < N_NODES) ? deg[base + 3] : 0;
    int sum = v0 + v1 + v2 + v3;
    s[t] = sum;
    __syncthreads();
    for (int d = 1; d < 256; d <<= 1) {
        int add = (t >= d) ? s[t - d] : 0;
        __syncthreads();
        s[t] += add;
        __syncthreads();
    }
    int excl = s[t] - sum;
    if (base + 0 < N_NODES) off[base + 0] = excl;
    excl += v0;
    if (base + 1 < N_NODES) off[base + 1] = excl;
    excl += v1;
    if (base + 2 < N_NODES) off[base + 2] = excl;
    excl += v2;
    if (base + 3 < N_NODES) off[base + 3] = excl;
    if (t == 255) partial[blockIdx.x] = s[255];
}

// ---------------- K3b: scan the 49 block partials (one wave) -------------
__global__ __launch_bounds__(64) void k_scan2(int* __restrict__ partial) {
    int t = threadIdx.x;
    int v = (t < SCAN_BLOCKS) ? partial[t] : 0;
    int orig = v;
#pragma unroll
    for (int d = 1; d < 64; d <<= 1) {
        int u = __shfl_up(v, d);
        if (t >= d) v += u;
    }
    if (t < SCAN_BLOCKS) partial[t] = v - orig;
}

// ---------------- K3c: add partial offsets, init cursor ------------------
__global__ __launch_bounds__(256) void k_scan3(const int* __restrict__ partial,
                                               int* __restrict__ off,
                                               int* __restrict__ cursor) {
    int i = blockIdx.x * 256 + threadIdx.x;
    if (i == 0) off[N_NODES] = EP;
    if (i < N_NODES) {
        int v = off[i] + partial[i >> 10];
        off[i] = v;
        cursor[i] = v;
    }
}

// ---------------- K4: scatter edge src ids into CSR ----------------------
__global__ __launch_bounds__(256) void k_scatter(const int* __restrict__ ei,
                                                 int* __restrict__ cursor,
                                                 int* __restrict__ csr_src) {
    int e = blockIdx.x * 256 + threadIdx.x;
    if (e >= EP) return;
    int s, d;
    if (e < E_EDGES) { s = ei[e]; d = ei[E_EDGES + e]; }
    else             { s = d = e - E_EDGES; }
    int pos = atomicAdd(&cursor[d], 1);
    csr_src[pos] = s;
}

// ---------------- K5: CSR gather-aggregate + softmax + ELU + pool --------
#define AGG_CHUNK 8
__global__ __launch_bounds__(128) void k_agg_pool(const int* __restrict__ off,
                                                  const int* __restrict__ csr_src,
                                                  const float* __restrict__ a_s,
                                                  const float* __restrict__ a_d,
                                                  const float* __restrict__ h,
                                                  const float* __restrict__ b1,
                                                  const int* __restrict__ batch,
                                                  float* __restrict__ g) {
    const int f = threadIdx.x;       // 0..127 feature channel
    const int head = f >> 5;         // 0..3
    const int n0 = blockIdx.x * AGG_CHUNK;
    int n1 = n0 + AGG_CHUNK;
    if (n1 > N_NODES) n1 = N_NODES;
    const float bias = b1[f];
    float pool = 0.f;
    int cur = batch[n0];
    for (int n = n0; n < n1; n++) {
        int b = batch[n];
        if (b != cur) {                        // uniform branch
            atomicAdd(&g[(size_t)cur * HC + f], pool);
            pool = 0.f;
            cur = b;
        }
        const float ad_h = a_d[(size_t)n * 4 + head];   // broadcast per head group
        const int rs = off[n], re = off[n + 1];
        float acc = 0.f, dsum = 0.f;
#pragma unroll 2
        for (int i = rs; i < re; i++) {
            int s = csr_src[i];                          // scalar broadcast
            float v = a_s[(size_t)s * 4 + head] + ad_h;  // 4-way broadcast gather
            v = v > 0.f ? v : NEG_SLOPE * v;
            float w = __expf(v);
            dsum += w;
            acc += w * h[(size_t)s * HC + f];            // coalesced 512B gather
        }
        float inv = 1.f / (dsum + 1e-16f);
        float val = acc * inv + bias;
        val = val > 0.f ? val : (__expf(val) - 1.f);     // ELU
        pool += val;
    }
    atomicAdd(&g[(size_t)cur * HC + f], pool);
}

// ---------------- K6: tiny 2-layer MLP on pooled graphs ------------------
__global__ __launch_bounds__(64) void k_mlp(const float* __restrict__ g,
                                            const float* __restrict__ w1,
                                            const float* __restrict__ bb1,
                                            const float* __restrict__ w2,
                                            const float* __restrict__ bb2,
                                            float* __restrict__ out) {
    __shared__ float sg[HC];
    __shared__ float st[HID];
    int b = blockIdx.x;
    int t = threadIdx.x;   // 64
    sg[t]      = g[(size_t)b * HC + t];
    sg[t + 64] = g[(size_t)b * HC + 64 + t];
    __syncthreads();
    if (t < HID) {
        float acc = bb1[t];
#pragma unroll 8
        for (int k = 0; k < HC; k++) acc += sg[k] * w1[(size_t)k * HID + t];
        st[t] = acc;
    }
    __syncthreads();
    if (t < OUT_CH) {
        float acc = bb2[t];
#pragma unroll
        for (int k = 0; k < HID; k++) acc += st[k] * w2[(size_t)k * OUT_CH + t];
        out[(size_t)b * OUT_CH + t] = acc;
    }
}

extern "C" void kernel_launch(void* const* d_in, const int* in_sizes, int n_in,
                              void* d_out, int out_size, void* d_ws, size_t ws_size,
                              hipStream_t stream) {
    const float* x       = (const float*)d_in[0];
    const int*   ei      = (const int*)d_in[1];
    const int*   batch   = (const int*)d_in[2];
    const float* W1      = (const float*)d_in[3];
    const float* att_src = (const float*)d_in[4];
    const float* att_dst = (const float*)d_in[5];
    const float* b1      = (const float*)d_in[6];
    const float* lin1_w  = (const float*)d_in[7];
    const float* lin1_b  = (const float*)d_in[8];
    const float* lin2_w  = (const float*)d_in[9];
    const float* lin2_b  = (const float*)d_in[10];
    float* out = (float*)d_out;

    float* ws = (float*)d_ws;
    // layout (float offsets):
    float*  h       = ws;                         // 6,400,000  (N*128)
    float*  a_s     = ws + 6400000;               //   200,000  (N*4)
    float*  a_d     = ws + 6600000;               //   200,000  (N*4)
    int*    csr_src = (int*)(ws + 6800000);       // 1,650,000
    int*    deg     = (int*)(ws + 8450000);       //    50,000
    int*    off     = (int*)(ws + 8500000);       //    50,001 (pad to 50,016)
    int*    cursor  = (int*)(ws + 8550016);       //    50,000
    int*    partial = (int*)(ws + 8600016);       //        64
    float*  g       = ws + 8600080;               //    65,536 (B*128)

    k_gemm_h<<<(N_NODES + NPB - 1) / NPB, 256, 0, stream>>>(
        x, W1, att_src, att_dst, h, a_s, a_d, deg);
    k_count<<<(EP + 255) / 256, 256, 0, stream>>>(ei, deg, g);
    k_scan1<<<SCAN_BLOCKS, 256, 0, stream>>>(deg, off, partial);
    k_scan2<<<1, 64, 0, stream>>>(partial);
    k_scan3<<<(N_NODES + 255) / 256, 256, 0, stream>>>(partial, off, cursor);
    k_scatter<<<(EP + 255) / 256, 256, 0, stream>>>(ei, cursor, csr_src);
    k_agg_pool<<<(N_NODES + AGG_CHUNK - 1) / AGG_CHUNK, 128, 0, stream>>>(
        off, csr_src, a_s, a_d, h, b1, batch, g);
    k_mlp<<<B_GRAPHS, 64, 0, stream>>>(g, lin1_w, lin1_b, lin2_w, lin2_b, out);
}